// Round 19
// baseline (152.439 us; speedup 1.0000x reference)
//
#include <hip/hip_runtime.h>
#include <hip/hip_bf16.h>

typedef __attribute__((ext_vector_type(8))) short short8;
typedef __attribute__((ext_vector_type(4))) float f32x4;

#define MFMA16(a,b,c) __builtin_amdgcn_mfma_f32_16x16x32_bf16((a),(b),(c),0,0,0)

static __device__ __forceinline__ unsigned int f2bf(float f){
    unsigned int u = __float_as_uint(f);
    u += 0x7FFFu + ((u >> 16) & 1u);
    return u >> 16;
}

static __device__ __forceinline__ short8 pack8(float4 a, float4 b){
    short8 r;
    r[0]=(short)f2bf(a.x); r[1]=(short)f2bf(a.y);
    r[2]=(short)f2bf(a.z); r[3]=(short)f2bf(a.w);
    r[4]=(short)f2bf(b.x); r[5]=(short)f2bf(b.y);
    r[6]=(short)f2bf(b.z); r[7]=(short)f2bf(b.w);
    return r;
}

// ---- mask -> bit-packed [b][q][32 words]; dtype sniff merged.
__global__ __launch_bounds__(256) void mask_prep_k(
    const unsigned int* __restrict__ m, unsigned int* __restrict__ bmout)
{
    __shared__ int any_hi;
    const int tid  = threadIdx.x;
    const int lane = tid & 63;
    const unsigned int gbase = blockIdx.x*256u + tid;
    if (tid == 0) any_hi = 0;

    unsigned int wv[8]; unsigned int acc = 0;
    #pragma unroll
    for (int it = 0; it < 8; ++it){
        wv[it] = m[it*262144u + gbase];
        acc |= wv[it];
    }
    __syncthreads();
    if (acc & 0xFFFFFF00u) atomicOr(&any_hi, 1);
    __syncthreads();

    if (any_hi == 0){
        for (int it = 0; it < 32; ++it){
            unsigned int idx = it*262144u + gbase;
            unsigned int v = m[idx];
            unsigned long long bal = __ballot(v != 0u);
            if (lane == 0)
                *(unsigned long long*)(bmout + (idx >> 5)) = bal;
        }
    } else {
        #pragma unroll
        for (int it = 0; it < 8; ++it){
            unsigned int idx = it*262144u + gbase;
            unsigned int v = wv[it];
            unsigned int nib = (v | (v>>7) | (v>>14) | (v>>21)) & 0xFu;
            unsigned int x = nib << ((lane & 7)*4);
            x |= (unsigned int)__shfl_xor((int)x, 1);
            x |= (unsigned int)__shfl_xor((int)x, 2);
            x |= (unsigned int)__shfl_xor((int)x, 4);
            if ((lane & 7) == 0)
                bmout[idx >> 3] = x;
        }
    }
}

// ---------------- QKV projection (3-way split grid) ----------------
__global__ __launch_bounds__(256) void qkv_proj_k(
    const float* __restrict__ nd,
    const float* __restrict__ Wqp, const float* __restrict__ bqp,
    const float* __restrict__ Wkp, const float* __restrict__ bkp,
    const float* __restrict__ Wvp, const float* __restrict__ bvp,
    unsigned short* __restrict__ qout, unsigned short* __restrict__ kout,
    unsigned short* __restrict__ vtout)
{
    __shared__ __align__(16) unsigned short xl[64*264];
    const int tid  = threadIdx.x;
    const int bi   = blockIdx.x;          // 384 = 3 kinds x 128 tiles
    const int kind = bi >> 7;
    const int R0   = (bi & 127) * 64;
    const int b    = R0 >> 10;
    const int n0   = R0 & 1023;

    #pragma unroll
    for (int it = 0; it < 16; ++it){
        int f4 = it*256 + tid;
        int r = f4 >> 6, c4 = f4 & 63;
        float4 v = *(const float4*)(nd + (size_t)(R0+r)*256 + c4*4);
        unsigned int lo = f2bf(v.x) | (f2bf(v.y) << 16);
        unsigned int hi = f2bf(v.z) | (f2bf(v.w) << 16);
        *(uint2*)&xl[r*264 + c4*4] = make_uint2(lo, hi);
    }
    __syncthreads();

    const int lane = tid & 63;
    const int w  = tid >> 6;
    const int ln = lane & 15;
    const int g  = lane >> 4;
    const int ow = w * 64;

    f32x4 acc[4][4];
    #pragma unroll
    for (int a=0;a<4;++a){
        #pragma unroll
        for (int c=0;c<4;++c) acc[a][c] = (f32x4){0.f,0.f,0.f,0.f};
    }

    if (kind < 2){
        const float* W  = kind ? Wkp : Wqp;
        const float* bb = kind ? bkp : bqp;
        unsigned short* op = kind ? kout : qout;
        const float scl = kind ? 1.0f : 0.17677669529663687f;
        for (int kk = 0; kk < 8; ++kk){
            short8 wf[4], xf[4];
            #pragma unroll
            for (int ot=0; ot<4; ++ot){
                const float* wp = W + (size_t)(ow + ot*16 + ln)*256 + kk*32 + g*8;
                wf[ot] = pack8(*(const float4*)wp, *(const float4*)(wp+4));
            }
            #pragma unroll
            for (int nt=0; nt<4; ++nt)
                xf[nt] = *(const short8*)&xl[(nt*16+ln)*264 + kk*32 + g*8];
            #pragma unroll
            for (int ot=0; ot<4; ++ot){
                #pragma unroll
                for (int nt=0; nt<4; ++nt)
                    acc[ot][nt] = MFMA16(wf[ot], xf[nt], acc[ot][nt]);
            }
        }
        #pragma unroll
        for (int ot=0; ot<4; ++ot){
            int o0 = ow + ot*16 + g*4;
            int h = o0 >> 5, d0 = o0 & 31;
            float4 b4 = *(const float4*)(bb + o0);
            #pragma unroll
            for (int nt=0; nt<4; ++nt){
                int n = n0 + nt*16 + ln;
                unsigned int lo = f2bf((acc[ot][nt][0]+b4.x)*scl) | (f2bf((acc[ot][nt][1]+b4.y)*scl)<<16);
                unsigned int hi = f2bf((acc[ot][nt][2]+b4.z)*scl) | (f2bf((acc[ot][nt][3]+b4.w)*scl)<<16);
                *(uint2*)(op + ((size_t)(b*8+h)*1024 + n)*32 + d0) = make_uint2(lo,hi);
            }
        }
    } else {
        for (int kk = 0; kk < 8; ++kk){
            short8 wf[4], xf[4];
            #pragma unroll
            for (int ot=0; ot<4; ++ot){
                const float* wp = Wvp + (size_t)(ow + ot*16 + ln)*256 + kk*32 + g*8;
                wf[ot] = pack8(*(const float4*)wp, *(const float4*)(wp+4));
            }
            #pragma unroll
            for (int nt=0; nt<4; ++nt)
                xf[nt] = *(const short8*)&xl[(nt*16+ln)*264 + kk*32 + g*8];
            #pragma unroll
            for (int nt=0; nt<4; ++nt){
                #pragma unroll
                for (int ot=0; ot<4; ++ot)
                    acc[nt][ot] = MFMA16(xf[nt], wf[ot], acc[nt][ot]);
            }
        }
        #pragma unroll
        for (int nt=0; nt<4; ++nt){
            int nb = n0 + nt*16 + g*4;
            #pragma unroll
            for (int ot=0; ot<4; ++ot){
                int o = ow + ot*16 + ln;
                int h = o >> 5, d = o & 31;
                float bvv = bvp[o];
                unsigned int lo = f2bf(acc[nt][ot][0]+bvv) | (f2bf(acc[nt][ot][1]+bvv)<<16);
                unsigned int hi = f2bf(acc[nt][ot][2]+bvv) | (f2bf(acc[nt][ot][3]+bvv)<<16);
                *(uint2*)(vtout + ((size_t)(b*8+h)*32 + d)*1024 + nb) = make_uint2(lo,hi);
            }
        }
    }
}

// ---------------- Fused biased-masked attention (r19 = r18 fixed) ---------
// r14's layout/compute + r17's no-drain barrier + DEPTH-2 bias prefetch:
// bias register sets A/B alternate; STAGE(chunk c) consumes regs whose loads
// were issued TWO iterations earlier (wait ~0), so >=1 chunk of HBM loads is
// always queued -> streaming instead of burst-and-stall. K/V/bm stay depth-1
// (L2-resident) with r14's snapshot-before-reload. Macros take register
// names as ARGUMENTS (r3 style) -- no token pasting against member access.
#define BARRIER_NODRAIN() \
    asm volatile("s_waitcnt lgkmcnt(0)\n\ts_barrier" ::: "memory")

__global__ __launch_bounds__(512, 4) void attn_k(
    const unsigned short* __restrict__ qbuf, const unsigned short* __restrict__ kbuf,
    const unsigned short* __restrict__ vtbuf, const float* __restrict__ bias,
    const unsigned int* __restrict__ bm, unsigned short* __restrict__ ab)
{
    __shared__ __align__(16) float bs[8704];   // [8h][16q][68] words = 34.8 KB
    const int tid  = threadIdx.x;
    const int bi   = blockIdx.x;        // 512 = 8 b * 64 q-tiles
    const int b    = bi >> 6;
    const int q0   = (bi & 63) * 16;
    const int lane = tid & 63;
    const int w    = tid >> 6;          // wave = head
    const int ln   = lane & 15;
    const int g    = lane >> 4;

    // Q fragment (B-operand): col=q=ln, k=d=g*8..
    const short8 qf = *(const short8*)(qbuf + ((size_t)(b*8+w)*1024 + q0 + ln)*32 + g*8);

    // kperm: tile-local row ln -> key 8*(ln>>2)+(ln&3); S^T keys/lane = 8g+j
    const int kperm = ((ln >> 2) << 3) + (ln & 3);
    const unsigned short* kp = kbuf  + ((size_t)(b*8+w)*1024 + kperm)*32 + g*8;
    const unsigned short* vp = vtbuf + ((size_t)(b*8+w)*32   + ln)*1024 + g*8;
    const unsigned int*  bmp = bm + (size_t)(b*1024 + q0 + ln)*32;

    // bias staging: thread t covers q'=t>>5, float4s idx=it*32+(t&31) of the
    // 512-float row-chunk; global float-off = idx*4 (k'=idx>>1, h'=(t&1)*4)
    const int sq  = tid >> 5;
    const float* bgp = bias + (size_t)(b*1024 + q0 + sq)*8192 + (tid & 31)*4;
    const int hqb = (tid & 1)*4*1088 + sq*68;          // LDS write base (words)
    const int kpw = (tid & 31) >> 1;                   // k' within 16-block
    // bias read base: [h=w][q=ln][k]: 2x b128 per half at +8g, +8g+4
    const int rb0 = w*1088 + ln*68 + 8*g;

    f32x4 acc0 = (f32x4){0.f,0.f,0.f,0.f};
    f32x4 acc1 = (f32x4){0.f,0.f,0.f,0.f};
    float lsum = 0.f;
    const f32x4 z4 = {0.f,0.f,0.f,0.f};

    float4 bA0, bA1, bA2, bA3;     // bias set A
    float4 bB0, bB1, bB2, bB3;     // bias set B
    short8 kn0, kn1, kn2, kn3;     // K depth-1
    unsigned int bm0, bm1;

#define LOAD_BIAS(R0_, R1_, R2_, R3_, cc) do { int c_ = (cc); \
    R0_ = *(const float4*)(bgp + (size_t)c_*512); \
    R1_ = *(const float4*)(bgp + (size_t)c_*512 + 128); \
    R2_ = *(const float4*)(bgp + (size_t)c_*512 + 256); \
    R3_ = *(const float4*)(bgp + (size_t)c_*512 + 384); } while(0)

#define LOAD_KVM(cc) do { int c_ = (cc); \
    kn0 = *(const short8*)(kp + c_*2048); \
    kn1 = *(const short8*)(kp + c_*2048 + 128); \
    kn2 = *(const short8*)(kp + c_*2048 + 1024); \
    kn3 = *(const short8*)(kp + c_*2048 + 1152); \
    bm0 = bmp[2*c_]; bm1 = bmp[2*c_+1]; } while(0)

#define STAGE1(R, IT) do { int kw_ = (IT)*16 + kpw; \
    bs[hqb        + kw_] = R.x; \
    bs[hqb + 1088 + kw_] = R.y; \
    bs[hqb + 2176 + kw_] = R.z; \
    bs[hqb + 3264 + kw_] = R.w; } while(0)

// one 32-key half (keys base=kh*32): kperm'd QK^T, b128 bias, exp, lazy-V PV
#define CHUNK_HALF(K0, K1, BMW, KH, VOFF) do { \
    f32x4 s0 = MFMA16(K0, qf, z4);   /* keys base+8g+0..3 */ \
    f32x4 s1 = MFMA16(K1, qf, z4);   /* keys base+8g+4..7 */ \
    f32x4 blo = *(const f32x4*)&bs[rb0 + (KH)*32]; \
    f32x4 bhi = *(const f32x4*)&bs[rb0 + (KH)*32 + 4]; \
    short8 vf0 = *(const short8*)(vp + (VOFF)); \
    short8 vf1 = *(const short8*)(vp + (VOFF) + 16*1024); \
    unsigned int mb_ = (BMW) >> (g*8); \
    float e0 = __expf(s0[0] + blo[0]); e0 = ((mb_>>0)&1u) ? 0.f : e0; \
    float e1 = __expf(s0[1] + blo[1]); e1 = ((mb_>>1)&1u) ? 0.f : e1; \
    float e2 = __expf(s0[2] + blo[2]); e2 = ((mb_>>2)&1u) ? 0.f : e2; \
    float e3 = __expf(s0[3] + blo[3]); e3 = ((mb_>>3)&1u) ? 0.f : e3; \
    float e4 = __expf(s1[0] + bhi[0]); e4 = ((mb_>>4)&1u) ? 0.f : e4; \
    float e5 = __expf(s1[1] + bhi[1]); e5 = ((mb_>>5)&1u) ? 0.f : e5; \
    float e6 = __expf(s1[2] + bhi[2]); e6 = ((mb_>>6)&1u) ? 0.f : e6; \
    float e7 = __expf(s1[3] + bhi[3]); e7 = ((mb_>>7)&1u) ? 0.f : e7; \
    lsum += ((e0+e1)+(e2+e3)) + ((e4+e5)+(e6+e7)); \
    int4 pw_ = make_int4( \
        (int)(f2bf(e0) | (f2bf(e1)<<16)), (int)(f2bf(e2) | (f2bf(e3)<<16)), \
        (int)(f2bf(e4) | (f2bf(e5)<<16)), (int)(f2bf(e6) | (f2bf(e7)<<16))); \
    short8 pf_ = *(short8*)&pw_; \
    acc0 = MFMA16(vf0, pf_, acc0); \
    acc1 = MFMA16(vf1, pf_, acc1); } while(0)

    // prologue: prime depth-2 bias pipeline + chunk-0 KVM
    LOAD_BIAS(bA0, bA1, bA2, bA3, 0);
    LOAD_BIAS(bB0, bB1, bB2, bB3, 1);
    LOAD_KVM(0);
    bm0 &= ~1u;                         // col 0 force-unmasked

    #pragma unroll 1
    for (int cc = 0; cc < 16; cc += 2){
        // ===== even iter: bias set A = chunk cc =====
        STAGE1(bA0, 0); STAGE1(bA1, 1); STAGE1(bA2, 2); STAGE1(bA3, 3);
        if (cc + 2 < 16) LOAD_BIAS(bA0, bA1, bA2, bA3, cc + 2);
        { short8 ck0 = kn0, ck1 = kn1, ck2 = kn2, ck3 = kn3;
          unsigned int cb0 = bm0, cb1 = bm1;
          if (cc + 1 < 16) LOAD_KVM(cc + 1);
          BARRIER_NODRAIN();
          CHUNK_HALF(ck0, ck1, cb0, 0, cc*64);
          CHUNK_HALF(ck2, ck3, cb1, 1, cc*64 + 32);
          BARRIER_NODRAIN(); }
        // ===== odd iter: bias set B = chunk cc+1 =====
        STAGE1(bB0, 0); STAGE1(bB1, 1); STAGE1(bB2, 2); STAGE1(bB3, 3);
        if (cc + 3 < 16) LOAD_BIAS(bB0, bB1, bB2, bB3, cc + 3);
        { short8 ck0 = kn0, ck1 = kn1, ck2 = kn2, ck3 = kn3;
          unsigned int cb0 = bm0, cb1 = bm1;
          if (cc + 2 < 16) LOAD_KVM(cc + 2);
          BARRIER_NODRAIN();
          CHUNK_HALF(ck0, ck1, cb0, 0, (cc+1)*64);
          CHUNK_HALF(ck2, ck3, cb1, 1, (cc+1)*64 + 32);
          BARRIER_NODRAIN(); }
    }

    float ps = lsum;
    ps += __shfl_xor(ps, 16);
    ps += __shfl_xor(ps, 32);
    float inv = 1.0f / ps;
    {
        int n = q0 + ln;
        unsigned int lo0 = f2bf(acc0[0]*inv) | (f2bf(acc0[1]*inv)<<16);
        unsigned int hi0 = f2bf(acc0[2]*inv) | (f2bf(acc0[3]*inv)<<16);
        *(uint2*)(ab + ((size_t)(b*1024 + n))*256 + w*32 + g*4) = make_uint2(lo0,hi0);
        unsigned int lo1 = f2bf(acc1[0]*inv) | (f2bf(acc1[1]*inv)<<16);
        unsigned int hi1 = f2bf(acc1[2]*inv) | (f2bf(acc1[3]*inv)<<16);
        *(uint2*)(ab + ((size_t)(b*1024 + n))*256 + w*32 + 16 + g*4) = make_uint2(lo1,hi1);
    }
#undef LOAD_BIAS
#undef LOAD_KVM
#undef STAGE1
#undef CHUNK_HALF
}

// ---------------- Output projection (32-row tiles) ----------------
__global__ __launch_bounds__(256) void oproj_k(
    const unsigned short* __restrict__ ab, const float* __restrict__ Wop,
    const float* __restrict__ bop, float* __restrict__ out)
{
    __shared__ __align__(16) unsigned short al[32*264];
    const int tid = threadIdx.x;
    const int R0 = blockIdx.x * 32;   // 256 blocks
    #pragma unroll
    for (int it=0; it<4; ++it){
        int f8 = it*256 + tid;
        int r = f8 >> 5, c8 = f8 & 31;
        *(short8*)&al[r*264 + c8*8] = *(const short8*)(ab + (size_t)(R0+r)*256 + c8*8);
    }
    __syncthreads();
    const int lane = tid & 63;
    const int w = tid >> 6, ln = lane & 15, g = lane >> 4;
    const int ow = w*64;
    f32x4 acc[4][2];
    #pragma unroll
    for (int a=0;a<4;++a){ acc[a][0]=(f32x4){0.f,0.f,0.f,0.f}; acc[a][1]=(f32x4){0.f,0.f,0.f,0.f}; }
    for (int kk=0;kk<8;++kk){
        short8 wf[4], xf[2];
        #pragma unroll
        for (int ot=0;ot<4;++ot){
            const float* wp = Wop + (size_t)(ow+ot*16+ln)*256 + kk*32 + g*8;
            wf[ot] = pack8(*(const float4*)wp, *(const float4*)(wp+4));
        }
        #pragma unroll
        for (int nt=0;nt<2;++nt)
            xf[nt] = *(const short8*)&al[(nt*16+ln)*264 + kk*32 + g*8];
        #pragma unroll
        for (int ot=0;ot<4;++ot){
            #pragma unroll
            for (int nt=0;nt<2;++nt)
                acc[ot][nt] = MFMA16(wf[ot], xf[nt], acc[ot][nt]);
        }
    }
    #pragma unroll
    for (int ot=0;ot<4;++ot){
        int o0 = ow + ot*16 + g*4;
        float4 b4 = *(const float4*)(bop + o0);
        #pragma unroll
        for (int nt=0;nt<2;++nt){
            int n = R0 + nt*16 + ln;
            float4 res;
            res.x = acc[ot][nt][0] + b4.x;
            res.y = acc[ot][nt][1] + b4.y;
            res.z = acc[ot][nt][2] + b4.z;
            res.w = acc[ot][nt][3] + b4.w;
            *(float4*)(out + (size_t)n*256 + o0) = res;
        }
    }
}

extern "C" void kernel_launch(void* const* d_in, const int* in_sizes, int n_in,
                              void* d_out, int out_size, void* d_ws, size_t ws_size,
                              hipStream_t stream)
{
    (void)in_sizes; (void)n_in; (void)out_size; (void)ws_size;
    const float* nd   = (const float*)d_in[0];
    // d_in[1] = N scalar (compile-time 1024 here)
    const float* bias = (const float*)d_in[2];
    const int* mask   = (const int*)d_in[3];
    const float* Wq = (const float*)d_in[4];
    const float* bq = (const float*)d_in[5];
    const float* Wk = (const float*)d_in[6];
    const float* bk = (const float*)d_in[7];
    const float* Wv = (const float*)d_in[8];
    const float* bv = (const float*)d_in[9];
    const float* Wo = (const float*)d_in[10];
    const float* bo = (const float*)d_in[11];
    float* out = (float*)d_out;

    const size_t ELEMS = (size_t)8*8*1024*32;   // 2M bf16 per buffer
    unsigned short* qb  = (unsigned short*)d_ws;
    unsigned short* kb  = qb  + ELEMS;
    unsigned short* vtb = kb  + ELEMS;
    unsigned short* ab  = vtb + ELEMS;
    unsigned int* bmw   = (unsigned int*)(ab + ELEMS);  // 1MB bitmask

    mask_prep_k<<<1024, 256, 0, stream>>>((const unsigned int*)mask, bmw);
    qkv_proj_k<<<384, 256, 0, stream>>>(nd, Wq, bq, Wk, bk, Wv, bv, qb, kb, vtb);
    attn_k<<<512, 512, 0, stream>>>(qb, kb, vtb, bias, bmw, ab);
    oproj_k<<<256, 256, 0, stream>>>(ab, Wo, bo, out);
}

// Round 20
// 146.947 us; speedup vs baseline: 1.0374x; 1.0374x over previous
//
#include <hip/hip_runtime.h>
#include <hip/hip_bf16.h>

typedef __attribute__((ext_vector_type(8))) short short8;
typedef __attribute__((ext_vector_type(4))) float f32x4;

#define MFMA16(a,b,c) __builtin_amdgcn_mfma_f32_16x16x32_bf16((a),(b),(c),0,0,0)

static __device__ __forceinline__ unsigned int f2bf(float f){
    unsigned int u = __float_as_uint(f);
    u += 0x7FFFu + ((u >> 16) & 1u);
    return u >> 16;
}

static __device__ __forceinline__ short8 pack8(float4 a, float4 b){
    short8 r;
    r[0]=(short)f2bf(a.x); r[1]=(short)f2bf(a.y);
    r[2]=(short)f2bf(a.z); r[3]=(short)f2bf(a.w);
    r[4]=(short)f2bf(b.x); r[5]=(short)f2bf(b.y);
    r[6]=(short)f2bf(b.z); r[7]=(short)f2bf(b.w);
    return r;
}

// ---- mask -> bit-packed [b][q][32 words]; dtype sniff merged.
__global__ __launch_bounds__(256) void mask_prep_k(
    const unsigned int* __restrict__ m, unsigned int* __restrict__ bmout)
{
    __shared__ int any_hi;
    const int tid  = threadIdx.x;
    const int lane = tid & 63;
    const unsigned int gbase = blockIdx.x*256u + tid;
    if (tid == 0) any_hi = 0;

    unsigned int wv[8]; unsigned int acc = 0;
    #pragma unroll
    for (int it = 0; it < 8; ++it){
        wv[it] = m[it*262144u + gbase];
        acc |= wv[it];
    }
    __syncthreads();
    if (acc & 0xFFFFFF00u) atomicOr(&any_hi, 1);
    __syncthreads();

    if (any_hi == 0){
        for (int it = 0; it < 32; ++it){
            unsigned int idx = it*262144u + gbase;
            unsigned int v = m[idx];
            unsigned long long bal = __ballot(v != 0u);
            if (lane == 0)
                *(unsigned long long*)(bmout + (idx >> 5)) = bal;
        }
    } else {
        #pragma unroll
        for (int it = 0; it < 8; ++it){
            unsigned int idx = it*262144u + gbase;
            unsigned int v = wv[it];
            unsigned int nib = (v | (v>>7) | (v>>14) | (v>>21)) & 0xFu;
            unsigned int x = nib << ((lane & 7)*4);
            x |= (unsigned int)__shfl_xor((int)x, 1);
            x |= (unsigned int)__shfl_xor((int)x, 2);
            x |= (unsigned int)__shfl_xor((int)x, 4);
            if ((lane & 7) == 0)
                bmout[idx >> 3] = x;
        }
    }
}

// ---------------- QKV projection (3-way split grid) ----------------
__global__ __launch_bounds__(256) void qkv_proj_k(
    const float* __restrict__ nd,
    const float* __restrict__ Wqp, const float* __restrict__ bqp,
    const float* __restrict__ Wkp, const float* __restrict__ bkp,
    const float* __restrict__ Wvp, const float* __restrict__ bvp,
    unsigned short* __restrict__ qout, unsigned short* __restrict__ kout,
    unsigned short* __restrict__ vtout)
{
    __shared__ __align__(16) unsigned short xl[64*264];
    const int tid  = threadIdx.x;
    const int bi   = blockIdx.x;          // 384 = 3 kinds x 128 tiles
    const int kind = bi >> 7;
    const int R0   = (bi & 127) * 64;
    const int b    = R0 >> 10;
    const int n0   = R0 & 1023;

    #pragma unroll
    for (int it = 0; it < 16; ++it){
        int f4 = it*256 + tid;
        int r = f4 >> 6, c4 = f4 & 63;
        float4 v = *(const float4*)(nd + (size_t)(R0+r)*256 + c4*4);
        unsigned int lo = f2bf(v.x) | (f2bf(v.y) << 16);
        unsigned int hi = f2bf(v.z) | (f2bf(v.w) << 16);
        *(uint2*)&xl[r*264 + c4*4] = make_uint2(lo, hi);
    }
    __syncthreads();

    const int lane = tid & 63;
    const int w  = tid >> 6;
    const int ln = lane & 15;
    const int g  = lane >> 4;
    const int ow = w * 64;

    f32x4 acc[4][4];
    #pragma unroll
    for (int a=0;a<4;++a){
        #pragma unroll
        for (int c=0;c<4;++c) acc[a][c] = (f32x4){0.f,0.f,0.f,0.f};
    }

    if (kind < 2){
        const float* W  = kind ? Wkp : Wqp;
        const float* bb = kind ? bkp : bqp;
        unsigned short* op = kind ? kout : qout;
        const float scl = kind ? 1.0f : 0.17677669529663687f;
        for (int kk = 0; kk < 8; ++kk){
            short8 wf[4], xf[4];
            #pragma unroll
            for (int ot=0; ot<4; ++ot){
                const float* wp = W + (size_t)(ow + ot*16 + ln)*256 + kk*32 + g*8;
                wf[ot] = pack8(*(const float4*)wp, *(const float4*)(wp+4));
            }
            #pragma unroll
            for (int nt=0; nt<4; ++nt)
                xf[nt] = *(const short8*)&xl[(nt*16+ln)*264 + kk*32 + g*8];
            #pragma unroll
            for (int ot=0; ot<4; ++ot){
                #pragma unroll
                for (int nt=0; nt<4; ++nt)
                    acc[ot][nt] = MFMA16(wf[ot], xf[nt], acc[ot][nt]);
            }
        }
        #pragma unroll
        for (int ot=0; ot<4; ++ot){
            int o0 = ow + ot*16 + g*4;
            int h = o0 >> 5, d0 = o0 & 31;
            float4 b4 = *(const float4*)(bb + o0);
            #pragma unroll
            for (int nt=0; nt<4; ++nt){
                int n = n0 + nt*16 + ln;
                unsigned int lo = f2bf((acc[ot][nt][0]+b4.x)*scl) | (f2bf((acc[ot][nt][1]+b4.y)*scl)<<16);
                unsigned int hi = f2bf((acc[ot][nt][2]+b4.z)*scl) | (f2bf((acc[ot][nt][3]+b4.w)*scl)<<16);
                *(uint2*)(op + ((size_t)(b*8+h)*1024 + n)*32 + d0) = make_uint2(lo,hi);
            }
        }
    } else {
        for (int kk = 0; kk < 8; ++kk){
            short8 wf[4], xf[4];
            #pragma unroll
            for (int ot=0; ot<4; ++ot){
                const float* wp = Wvp + (size_t)(ow + ot*16 + ln)*256 + kk*32 + g*8;
                wf[ot] = pack8(*(const float4*)wp, *(const float4*)(wp+4));
            }
            #pragma unroll
            for (int nt=0; nt<4; ++nt)
                xf[nt] = *(const short8*)&xl[(nt*16+ln)*264 + kk*32 + g*8];
            #pragma unroll
            for (int nt=0; nt<4; ++nt){
                #pragma unroll
                for (int ot=0; ot<4; ++ot)
                    acc[nt][ot] = MFMA16(xf[nt], wf[ot], acc[nt][ot]);
            }
        }
        #pragma unroll
        for (int nt=0; nt<4; ++nt){
            int nb = n0 + nt*16 + g*4;
            #pragma unroll
            for (int ot=0; ot<4; ++ot){
                int o = ow + ot*16 + ln;
                int h = o >> 5, d = o & 31;
                float bvv = bvp[o];
                unsigned int lo = f2bf(acc[nt][ot][0]+bvv) | (f2bf(acc[nt][ot][1]+bvv)<<16);
                unsigned int hi = f2bf(acc[nt][ot][2]+bvv) | (f2bf(acc[nt][ot][3]+bvv)<<16);
                *(uint2*)(vtout + ((size_t)(b*8+h)*32 + d)*1024 + nb) = make_uint2(lo,hi);
            }
        }
    }
}

// ---------------- Fused biased-masked attention (r20: split-K x2) ---------
// Grid 1024 = kq(2, HIGH bit) x b(8) x qt(64). Block 256 thr = 4 waves x
// 2 heads/wave -> block spans all 8 heads (bias tile shared in-block, no
// traffic duplication; kq halves read disjoint bias/K/V/mask). 32-key
// chunks x16 iters. LDS [8h][16q][36] = 18.4 KB -> 4 blocks/CU = 16 waves
// in 4 INDEPENDENT barrier domains (r14 had 2). Compute = r14's kperm
// machinery per head; fixed-max softmax -> halves exactly additive.
__global__ __launch_bounds__(256, 4) void attn_k(
    const unsigned short* __restrict__ qbuf, const unsigned short* __restrict__ kbuf,
    const unsigned short* __restrict__ vtbuf, const float* __restrict__ bias,
    const unsigned int* __restrict__ bm, float* __restrict__ opart,
    float* __restrict__ lpart)
{
    __shared__ __align__(16) float bs[4608];   // [8h][16q][36] words = 18.4 KB
    const int tid  = threadIdx.x;
    const int bi   = blockIdx.x;        // 1024 = kq(2 high) x b(8) x qt(64)
    const int kq   = bi >> 9;
    const int b    = (bi >> 6) & 7;
    const int q0   = (bi & 63) * 16;
    const int lane = tid & 63;
    const int w    = tid >> 6;          // wave id; heads 2w, 2w+1
    const int ln   = lane & 15;
    const int g    = lane >> 4;
    const int h0   = 2*w, h1 = 2*w + 1;

    // Q fragments (B-operand): col=q=ln, k=d=g*8..
    const short8 qf0 = *(const short8*)(qbuf + ((size_t)(b*8+h0)*1024 + q0 + ln)*32 + g*8);
    const short8 qf1 = *(const short8*)(qbuf + ((size_t)(b*8+h1)*1024 + q0 + ln)*32 + g*8);

    // kperm: tile-local row ln -> key 8*(ln>>2)+(ln&3); S^T keys/lane = 8g+j
    const int kperm = ((ln >> 2) << 3) + (ln & 3);
    const unsigned short* kpA = kbuf + ((size_t)(b*8+h0)*1024 + kperm)*32 + g*8;
    const unsigned short* kpB = kbuf + ((size_t)(b*8+h1)*1024 + kperm)*32 + g*8;
    const unsigned short* vpA = vtbuf + ((size_t)(b*8+h0)*32 + ln)*1024 + g*8;
    const unsigned short* vpB = vtbuf + ((size_t)(b*8+h1)*32 + ln)*1024 + g*8;
    const unsigned int*  bmp = bm + (size_t)(b*1024 + q0 + ln)*32;

    // bias staging: thread t covers q'=t>>4 (16 thr/row); float4 f=(t&15)+it*16
    // of the 256-float (32-key) row-chunk; h'=(t&1)*4, k'=it*8+((t&15)>>1)
    const int sq  = tid >> 4;
    const float* bgp = bias + (size_t)(b*1024 + q0 + sq)*8192 + (tid & 15)*4;
    const int hqb = (tid & 1)*4*576 + sq*36;           // LDS write base (words)
    const int kpw = (tid & 15) >> 1;
    // bias read bases: [h][q=ln][k]: b128 pair at +8g, +8g+4
    const int rb0 = h0*576 + ln*36 + 8*g;
    const int rb1 = rb0 + 576;

    f32x4 acc00 = (f32x4){0.f,0.f,0.f,0.f};   // h0, d0-15
    f32x4 acc01 = (f32x4){0.f,0.f,0.f,0.f};   // h0, d16-31
    f32x4 acc10 = (f32x4){0.f,0.f,0.f,0.f};
    f32x4 acc11 = (f32x4){0.f,0.f,0.f,0.f};
    float lsum0 = 0.f, lsum1 = 0.f;
    const f32x4 z4 = {0.f,0.f,0.f,0.f};

    float4 br0, br1, br2, br3;
    short8 knA0, knA1, knB0, knB1;
    unsigned int bm0;

#define LOAD_ALL(cc) do { int c_ = (cc); \
    br0 = *(const float4*)(bgp + (size_t)c_*256); \
    br1 = *(const float4*)(bgp + (size_t)c_*256 + 64); \
    br2 = *(const float4*)(bgp + (size_t)c_*256 + 128); \
    br3 = *(const float4*)(bgp + (size_t)c_*256 + 192); \
    knA0 = *(const short8*)(kpA + c_*1024); \
    knA1 = *(const short8*)(kpA + c_*1024 + 128); \
    knB0 = *(const short8*)(kpB + c_*1024); \
    knB1 = *(const short8*)(kpB + c_*1024 + 128); \
    bm0 = bmp[c_]; } while(0)

#define STAGE1(R, IT) do { int kw_ = (IT)*8 + kpw; \
    bs[hqb        + kw_] = R.x; \
    bs[hqb +  576 + kw_] = R.y; \
    bs[hqb + 1152 + kw_] = R.z; \
    bs[hqb + 1728 + kw_] = R.w; } while(0)

// one head's 32-key chunk: kperm'd QK^T, b128 bias, exp, lazy-V PV (r14)
#define CHUNK32(K0, K1, QF, RB, VP, VOFF, BMW, ACCL, ACCH, LSUM) do { \
    f32x4 s0 = MFMA16(K0, QF, z4);   /* keys 8g+0..3 */ \
    f32x4 s1 = MFMA16(K1, QF, z4);   /* keys 8g+4..7 */ \
    f32x4 blo = *(const f32x4*)&bs[RB]; \
    f32x4 bhi = *(const f32x4*)&bs[RB + 4]; \
    short8 vf0 = *(const short8*)(VP + (VOFF)); \
    short8 vf1 = *(const short8*)(VP + (VOFF) + 16*1024); \
    unsigned int mb_ = (BMW) >> (g*8); \
    float e0 = __expf(s0[0] + blo[0]); e0 = ((mb_>>0)&1u) ? 0.f : e0; \
    float e1 = __expf(s0[1] + blo[1]); e1 = ((mb_>>1)&1u) ? 0.f : e1; \
    float e2 = __expf(s0[2] + blo[2]); e2 = ((mb_>>2)&1u) ? 0.f : e2; \
    float e3 = __expf(s0[3] + blo[3]); e3 = ((mb_>>3)&1u) ? 0.f : e3; \
    float e4 = __expf(s1[0] + bhi[0]); e4 = ((mb_>>4)&1u) ? 0.f : e4; \
    float e5 = __expf(s1[1] + bhi[1]); e5 = ((mb_>>5)&1u) ? 0.f : e5; \
    float e6 = __expf(s1[2] + bhi[2]); e6 = ((mb_>>6)&1u) ? 0.f : e6; \
    float e7 = __expf(s1[3] + bhi[3]); e7 = ((mb_>>7)&1u) ? 0.f : e7; \
    LSUM += ((e0+e1)+(e2+e3)) + ((e4+e5)+(e6+e7)); \
    int4 pw_ = make_int4( \
        (int)(f2bf(e0) | (f2bf(e1)<<16)), (int)(f2bf(e2) | (f2bf(e3)<<16)), \
        (int)(f2bf(e4) | (f2bf(e5)<<16)), (int)(f2bf(e6) | (f2bf(e7)<<16))); \
    short8 pf_ = *(short8*)&pw_; \
    ACCL = MFMA16(vf0, pf_, ACCL); \
    ACCH = MFMA16(vf1, pf_, ACCH); } while(0)

    // prologue: first chunk of this half
    LOAD_ALL(kq*16);
    if (kq == 0) bm0 &= ~1u;            // col 0 force-unmasked (chunk 0 only)

    #pragma unroll 1
    for (int cc = 0; cc < 16; ++cc){
        const int c = kq*16 + cc;
        STAGE1(br0, 0); STAGE1(br1, 1); STAGE1(br2, 2); STAGE1(br3, 3);
        // snapshot K/mask of current chunk BEFORE reload (r6 lesson)
        short8 cA0 = knA0, cA1 = knA1, cB0 = knB0, cB1 = knB1;
        unsigned int cb = bm0;
        if (cc + 1 < 16) LOAD_ALL(c + 1);
        __syncthreads();

        CHUNK32(cA0, cA1, qf0, rb0, vpA, c*32, cb, acc00, acc01, lsum0);
        CHUNK32(cB0, cB1, qf1, rb1, vpB, c*32, cb, acc10, acc11, lsum1);
        __syncthreads();
    }

    // epilogue: unnormalized partials + denominators (r9-proven combine fmt)
    #pragma unroll
    for (int h2 = 0; h2 < 2; ++h2){
        float ps = h2 ? lsum1 : lsum0;
        ps += __shfl_xor(ps, 16);
        ps += __shfl_xor(ps, 32);
        size_t row = ((size_t)(kq*8 + b)*1024 + q0 + ln)*8 + (2*w + h2);
        if (g == 0) lpart[row] = ps;
        float* ob = opart + row*32;
        f32x4 aL = h2 ? acc10 : acc00;
        f32x4 aH = h2 ? acc11 : acc01;
        *(float4*)(ob + g*4)      = make_float4(aL[0], aL[1], aL[2], aL[3]);
        *(float4*)(ob + 16 + g*4) = make_float4(aH[0], aH[1], aH[2], aH[3]);
    }
#undef LOAD_ALL
#undef STAGE1
#undef CHUNK32
}

// ---------------- split-K combine: ab = (sum Opart) / (sum l) ----------------
__global__ __launch_bounds__(256) void combine_k(
    const float* __restrict__ op, const float* __restrict__ lp,
    unsigned short* __restrict__ ab)
{
    const size_t STR = (size_t)8*1024*8*32;   // 2M floats per partial
    int idx = blockIdx.x*256 + threadIdx.x;   // float4 index, 524288 total
    size_t off = (size_t)idx * 4;
    float4 s0 = *(const float4*)(op + off);
    float4 s1 = *(const float4*)(op + STR + off);
    int bqh = idx >> 3;                        // (b*1024+q)*8+h
    float l = lp[bqh] + lp[65536 + bqh];
    float inv = 1.0f / l;
    float rx = (s0.x + s1.x) * inv;
    float ry = (s0.y + s1.y) * inv;
    float rz = (s0.z + s1.z) * inv;
    float rw = (s0.w + s1.w) * inv;
    unsigned int lo = f2bf(rx) | (f2bf(ry) << 16);
    unsigned int hi = f2bf(rz) | (f2bf(rw) << 16);
    *(uint2*)(ab + off) = make_uint2(lo, hi);
}

// ---------------- Output projection (32-row tiles) ----------------
__global__ __launch_bounds__(256) void oproj_k(
    const unsigned short* __restrict__ ab, const float* __restrict__ Wop,
    const float* __restrict__ bop, float* __restrict__ out)
{
    __shared__ __align__(16) unsigned short al[32*264];
    const int tid = threadIdx.x;
    const int R0 = blockIdx.x * 32;   // 256 blocks
    #pragma unroll
    for (int it=0; it<4; ++it){
        int f8 = it*256 + tid;
        int r = f8 >> 5, c8 = f8 & 31;
        *(short8*)&al[r*264 + c8*8] = *(const short8*)(ab + (size_t)(R0+r)*256 + c8*8);
    }
    __syncthreads();
    const int lane = tid & 63;
    const int w = tid >> 6, ln = lane & 15, g = lane >> 4;
    const int ow = w*64;
    f32x4 acc[4][2];
    #pragma unroll
    for (int a=0;a<4;++a){ acc[a][0]=(f32x4){0.f,0.f,0.f,0.f}; acc[a][1]=(f32x4){0.f,0.f,0.f,0.f}; }
    for (int kk=0;kk<8;++kk){
        short8 wf[4], xf[2];
        #pragma unroll
        for (int ot=0;ot<4;++ot){
            const float* wp = Wop + (size_t)(ow+ot*16+ln)*256 + kk*32 + g*8;
            wf[ot] = pack8(*(const float4*)wp, *(const float4*)(wp+4));
        }
        #pragma unroll
        for (int nt=0;nt<2;++nt)
            xf[nt] = *(const short8*)&al[(nt*16+ln)*264 + kk*32 + g*8];
        #pragma unroll
        for (int ot=0;ot<4;++ot){
            #pragma unroll
            for (int nt=0;nt<2;++nt)
                acc[ot][nt] = MFMA16(wf[ot], xf[nt], acc[ot][nt]);
        }
    }
    #pragma unroll
    for (int ot=0;ot<4;++ot){
        int o0 = ow + ot*16 + g*4;
        float4 b4 = *(const float4*)(bop + o0);
        #pragma unroll
        for (int nt=0;nt<2;++nt){
            int n = R0 + nt*16 + ln;
            float4 res;
            res.x = acc[ot][nt][0] + b4.x;
            res.y = acc[ot][nt][1] + b4.y;
            res.z = acc[ot][nt][2] + b4.z;
            res.w = acc[ot][nt][3] + b4.w;
            *(float4*)(out + (size_t)n*256 + o0) = res;
        }
    }
}

extern "C" void kernel_launch(void* const* d_in, const int* in_sizes, int n_in,
                              void* d_out, int out_size, void* d_ws, size_t ws_size,
                              hipStream_t stream)
{
    (void)in_sizes; (void)n_in; (void)out_size; (void)ws_size;
    const float* nd   = (const float*)d_in[0];
    // d_in[1] = N scalar (compile-time 1024 here)
    const float* bias = (const float*)d_in[2];
    const int* mask   = (const int*)d_in[3];
    const float* Wq = (const float*)d_in[4];
    const float* bq = (const float*)d_in[5];
    const float* Wk = (const float*)d_in[6];
    const float* bk = (const float*)d_in[7];
    const float* Wv = (const float*)d_in[8];
    const float* bv = (const float*)d_in[9];
    const float* Wo = (const float*)d_in[10];
    const float* bo = (const float*)d_in[11];
    float* out = (float*)d_out;

    const size_t ELEMS = (size_t)8*8*1024*32;   // 2M bf16 per buffer
    unsigned short* qb  = (unsigned short*)d_ws;
    unsigned short* kb  = qb  + ELEMS;
    unsigned short* vtb = kb  + ELEMS;
    unsigned short* ab  = vtb + ELEMS;
    unsigned int* bmw   = (unsigned int*)(ab + ELEMS);     // 1MB bitmask
    float* opart        = (float*)(bmw + 262144);          // 2 x 8MB f32
    float* lpart        = opart + (size_t)2*ELEMS;         // 2 x 256KB f32

    mask_prep_k<<<1024, 256, 0, stream>>>((const unsigned int*)mask, bmw);
    qkv_proj_k<<<384, 256, 0, stream>>>(nd, Wq, bq, Wk, bk, Wv, bv, qb, kb, vtb);
    attn_k<<<1024, 256, 0, stream>>>(qb, kb, vtb, bias, bmw, opart, lpart);
    combine_k<<<2048, 256, 0, stream>>>(opart, lpart, ab);
    oproj_k<<<256, 256, 0, stream>>>(ab, Wo, bo, out);
}

// Round 22
// 137.290 us; speedup vs baseline: 1.1103x; 1.0703x over previous
//
#include <hip/hip_runtime.h>
#include <hip/hip_bf16.h>

typedef __attribute__((ext_vector_type(8))) short short8;
typedef __attribute__((ext_vector_type(4))) float f32x4;

#define MFMA16(a,b,c) __builtin_amdgcn_mfma_f32_16x16x32_bf16((a),(b),(c),0,0,0)

static __device__ __forceinline__ unsigned int f2bf(float f){
    unsigned int u = __float_as_uint(f);
    u += 0x7FFFu + ((u >> 16) & 1u);
    return u >> 16;
}

static __device__ __forceinline__ short8 pack8(float4 a, float4 b){
    short8 r;
    r[0]=(short)f2bf(a.x); r[1]=(short)f2bf(a.y);
    r[2]=(short)f2bf(a.z); r[3]=(short)f2bf(a.w);
    r[4]=(short)f2bf(b.x); r[5]=(short)f2bf(b.y);
    r[6]=(short)f2bf(b.z); r[7]=(short)f2bf(b.w);
    return r;
}

// ---------------- Merged: QKV projection (blocks 0..383) +
//                  mask bit-pack (blocks 384..1407) -----------------------
__global__ __launch_bounds__(256) void qkv_mask_k(
    const float* __restrict__ nd,
    const float* __restrict__ Wqp, const float* __restrict__ bqp,
    const float* __restrict__ Wkp, const float* __restrict__ bkp,
    const float* __restrict__ Wvp, const float* __restrict__ bvp,
    unsigned short* __restrict__ qout, unsigned short* __restrict__ kout,
    unsigned short* __restrict__ vtout,
    const unsigned int* __restrict__ m, unsigned int* __restrict__ bmout)
{
    __shared__ __align__(16) unsigned short xl[64*264];
    const int tid  = threadIdx.x;

    if (blockIdx.x >= 384){
        // ------- mask path (1024 blocks): dtype sniff + bit-pack -------
        __shared__ int any_hi;
        const int lane = tid & 63;
        const unsigned int gbase = (blockIdx.x - 384)*256u + tid;
        if (tid == 0) any_hi = 0;
        unsigned int wv[8]; unsigned int acc = 0;
        #pragma unroll
        for (int it = 0; it < 8; ++it){
            wv[it] = __builtin_nontemporal_load(m + it*262144u + gbase);
            acc |= wv[it];
        }
        __syncthreads();
        if (acc & 0xFFFFFF00u) atomicOr(&any_hi, 1);
        __syncthreads();
        if (any_hi == 0){
            for (int it = 0; it < 32; ++it){
                unsigned int idx = it*262144u + gbase;
                unsigned int v = __builtin_nontemporal_load(m + idx);
                unsigned long long bal = __ballot(v != 0u);
                if (lane == 0)
                    *(unsigned long long*)(bmout + (idx >> 5)) = bal;
            }
        } else {
            #pragma unroll
            for (int it = 0; it < 8; ++it){
                unsigned int idx = it*262144u + gbase;
                unsigned int v = wv[it];
                unsigned int nib = (v | (v>>7) | (v>>14) | (v>>21)) & 0xFu;
                unsigned int x = nib << ((lane & 7)*4);
                x |= (unsigned int)__shfl_xor((int)x, 1);
                x |= (unsigned int)__shfl_xor((int)x, 2);
                x |= (unsigned int)__shfl_xor((int)x, 4);
                if ((lane & 7) == 0)
                    bmout[idx >> 3] = x;
            }
        }
        return;
    }

    // ---------------- qkv path (blocks 0..383) ----------------
    const int bi   = blockIdx.x;          // 384 = 3 kinds x 128 tiles
    const int kind = bi >> 7;
    const int R0   = (bi & 127) * 64;
    const int b    = R0 >> 10;
    const int n0   = R0 & 1023;

    #pragma unroll
    for (int it = 0; it < 16; ++it){
        int f4 = it*256 + tid;
        int r = f4 >> 6, c4 = f4 & 63;
        float4 v = *(const float4*)(nd + (size_t)(R0+r)*256 + c4*4);
        unsigned int lo = f2bf(v.x) | (f2bf(v.y) << 16);
        unsigned int hi = f2bf(v.z) | (f2bf(v.w) << 16);
        *(uint2*)&xl[r*264 + c4*4] = make_uint2(lo, hi);
    }
    __syncthreads();

    const int lane = tid & 63;
    const int w  = tid >> 6;
    const int ln = lane & 15;
    const int g  = lane >> 4;
    const int ow = w * 64;

    f32x4 acc[4][4];
    #pragma unroll
    for (int a=0;a<4;++a){
        #pragma unroll
        for (int c=0;c<4;++c) acc[a][c] = (f32x4){0.f,0.f,0.f,0.f};
    }

    if (kind < 2){
        const float* W  = kind ? Wkp : Wqp;
        const float* bb = kind ? bkp : bqp;
        unsigned short* op = kind ? kout : qout;
        const float scl = kind ? 1.0f : 0.17677669529663687f;
        for (int kk = 0; kk < 8; ++kk){
            short8 wf[4], xf[4];
            #pragma unroll
            for (int ot=0; ot<4; ++ot){
                const float* wp = W + (size_t)(ow + ot*16 + ln)*256 + kk*32 + g*8;
                wf[ot] = pack8(*(const float4*)wp, *(const float4*)(wp+4));
            }
            #pragma unroll
            for (int nt=0; nt<4; ++nt)
                xf[nt] = *(const short8*)&xl[(nt*16+ln)*264 + kk*32 + g*8];
            #pragma unroll
            for (int ot=0; ot<4; ++ot){
                #pragma unroll
                for (int nt=0; nt<4; ++nt)
                    acc[ot][nt] = MFMA16(wf[ot], xf[nt], acc[ot][nt]);
            }
        }
        #pragma unroll
        for (int ot=0; ot<4; ++ot){
            int o0 = ow + ot*16 + g*4;
            int h = o0 >> 5, d0 = o0 & 31;
            float4 b4 = *(const float4*)(bb + o0);
            #pragma unroll
            for (int nt=0; nt<4; ++nt){
                int n = n0 + nt*16 + ln;
                unsigned int lo = f2bf((acc[ot][nt][0]+b4.x)*scl) | (f2bf((acc[ot][nt][1]+b4.y)*scl)<<16);
                unsigned int hi = f2bf((acc[ot][nt][2]+b4.z)*scl) | (f2bf((acc[ot][nt][3]+b4.w)*scl)<<16);
                *(uint2*)(op + ((size_t)(b*8+h)*1024 + n)*32 + d0) = make_uint2(lo,hi);
            }
        }
    } else {
        for (int kk = 0; kk < 8; ++kk){
            short8 wf[4], xf[4];
            #pragma unroll
            for (int ot=0; ot<4; ++ot){
                const float* wp = Wvp + (size_t)(ow + ot*16 + ln)*256 + kk*32 + g*8;
                wf[ot] = pack8(*(const float4*)wp, *(const float4*)(wp+4));
            }
            #pragma unroll
            for (int nt=0; nt<4; ++nt)
                xf[nt] = *(const short8*)&xl[(nt*16+ln)*264 + kk*32 + g*8];
            #pragma unroll
            for (int nt=0; nt<4; ++nt){
                #pragma unroll
                for (int ot=0; ot<4; ++ot)
                    acc[nt][ot] = MFMA16(xf[nt], wf[ot], acc[nt][ot]);
            }
        }
        #pragma unroll
        for (int nt=0; nt<4; ++nt){
            int nb = n0 + nt*16 + g*4;
            #pragma unroll
            for (int ot=0; ot<4; ++ot){
                int o = ow + ot*16 + ln;
                int h = o >> 5, d = o & 31;
                float bvv = bvp[o];
                unsigned int lo = f2bf(acc[nt][ot][0]+bvv) | (f2bf(acc[nt][ot][1]+bvv)<<16);
                unsigned int hi = f2bf(acc[nt][ot][2]+bvv) | (f2bf(acc[nt][ot][3]+bvv)<<16);
                *(uint2*)(vtout + ((size_t)(b*8+h)*32 + d)*1024 + nb) = make_uint2(lo,hi);
            }
        }
    }
}

// ---------------- Fused biased-masked attention (r22 = r21 fixed) ---------
// r14 BYTE-IDENTICAL machinery; only change: bias loads are NON-TEMPORAL
// (evict-first) so the 268MB read-once bias stream stops thrashing K/V out
// of the per-XCD L2s. Nontemporal loads use ext-vector f32x4 (the builtin
// rejects HIP_vector_type float4 pointers -- r21's compile error).
__global__ __launch_bounds__(512, 4) void attn_k(
    const unsigned short* __restrict__ qbuf, const unsigned short* __restrict__ kbuf,
    const unsigned short* __restrict__ vtbuf, const float* __restrict__ bias,
    const unsigned int* __restrict__ bm, unsigned short* __restrict__ ab)
{
    __shared__ __align__(16) float bs[8704];   // [8h][16q][68] words = 34.8 KB
    const int tid  = threadIdx.x;
    const int bi   = blockIdx.x;        // 512 = 8 b * 64 q-tiles
    const int b    = bi >> 6;
    const int q0   = (bi & 63) * 16;
    const int lane = tid & 63;
    const int w    = tid >> 6;          // wave = head
    const int ln   = lane & 15;
    const int g    = lane >> 4;

    // Q fragment (B-operand): col=q=ln, k=d=g*8..
    const short8 qf = *(const short8*)(qbuf + ((size_t)(b*8+w)*1024 + q0 + ln)*32 + g*8);

    // kperm: tile-local row ln -> key 8*(ln>>2)+(ln&3); S^T keys/lane = 8g+j
    const int kperm = ((ln >> 2) << 3) + (ln & 3);
    const unsigned short* kp = kbuf  + ((size_t)(b*8+w)*1024 + kperm)*32 + g*8;
    const unsigned short* vp = vtbuf + ((size_t)(b*8+w)*32   + ln)*1024 + g*8;
    const unsigned int*  bmp = bm + (size_t)(b*1024 + q0 + ln)*32;

    // bias staging: thread t covers q'=t>>5, float4s idx=it*32+(t&31) of the
    // 512-float row-chunk; global float-off = idx*4 (k'=idx>>1, h'=(t&1)*4)
    const int sq  = tid >> 5;
    const float* bgp = bias + (size_t)(b*1024 + q0 + sq)*8192 + (tid & 31)*4;
    const int hqb = (tid & 1)*4*1088 + sq*68;          // LDS write base (words)
    const int kpw = (tid & 31) >> 1;                   // k' within 16-block
    // bias read base: [h=w][q=ln][k]: 2x b128 per half at +8g, +8g+4
    const int rb0 = w*1088 + ln*68 + 8*g;

    f32x4 acc0 = (f32x4){0.f,0.f,0.f,0.f};
    f32x4 acc1 = (f32x4){0.f,0.f,0.f,0.f};
    float lsum = 0.f;
    const f32x4 z4 = {0.f,0.f,0.f,0.f};

    f32x4 br0, br1, br2, br3;          // ext-vector: nontemporal-compatible
    short8 kn0, kn1, kn2, kn3;
    unsigned int bm0, bm1;

#define LOAD_ALL(cc) do { int c_ = (cc); \
    br0 = __builtin_nontemporal_load((const f32x4*)(bgp + (size_t)c_*512)); \
    br1 = __builtin_nontemporal_load((const f32x4*)(bgp + (size_t)c_*512 + 128)); \
    br2 = __builtin_nontemporal_load((const f32x4*)(bgp + (size_t)c_*512 + 256)); \
    br3 = __builtin_nontemporal_load((const f32x4*)(bgp + (size_t)c_*512 + 384)); \
    kn0 = *(const short8*)(kp + c_*2048); \
    kn1 = *(const short8*)(kp + c_*2048 + 128); \
    kn2 = *(const short8*)(kp + c_*2048 + 1024); \
    kn3 = *(const short8*)(kp + c_*2048 + 1152); \
    bm0 = bmp[2*c_]; bm1 = bmp[2*c_+1]; } while(0)

#define STAGE1(R, IT) do { int kw_ = (IT)*16 + kpw; \
    bs[hqb        + kw_] = R[0]; \
    bs[hqb + 1088 + kw_] = R[1]; \
    bs[hqb + 2176 + kw_] = R[2]; \
    bs[hqb + 3264 + kw_] = R[3]; } while(0)

// one 32-key half (keys base=kh*32): kperm'd QK^T, b128 bias, exp, lazy-V PV
#define CHUNK_HALF(K0, K1, BMW, KH, VOFF) do { \
    f32x4 s0 = MFMA16(K0, qf, z4);   /* keys base+8g+0..3 */ \
    f32x4 s1 = MFMA16(K1, qf, z4);   /* keys base+8g+4..7 */ \
    f32x4 blo = *(const f32x4*)&bs[rb0 + (KH)*32]; \
    f32x4 bhi = *(const f32x4*)&bs[rb0 + (KH)*32 + 4]; \
    short8 vf0 = *(const short8*)(vp + (VOFF)); \
    short8 vf1 = *(const short8*)(vp + (VOFF) + 16*1024); \
    unsigned int mb_ = (BMW) >> (g*8); \
    float e0 = __expf(s0[0] + blo[0]); e0 = ((mb_>>0)&1u) ? 0.f : e0; \
    float e1 = __expf(s0[1] + blo[1]); e1 = ((mb_>>1)&1u) ? 0.f : e1; \
    float e2 = __expf(s0[2] + blo[2]); e2 = ((mb_>>2)&1u) ? 0.f : e2; \
    float e3 = __expf(s0[3] + blo[3]); e3 = ((mb_>>3)&1u) ? 0.f : e3; \
    float e4 = __expf(s1[0] + bhi[0]); e4 = ((mb_>>4)&1u) ? 0.f : e4; \
    float e5 = __expf(s1[1] + bhi[1]); e5 = ((mb_>>5)&1u) ? 0.f : e5; \
    float e6 = __expf(s1[2] + bhi[2]); e6 = ((mb_>>6)&1u) ? 0.f : e6; \
    float e7 = __expf(s1[3] + bhi[3]); e7 = ((mb_>>7)&1u) ? 0.f : e7; \
    lsum += ((e0+e1)+(e2+e3)) + ((e4+e5)+(e6+e7)); \
    int4 pw_ = make_int4( \
        (int)(f2bf(e0) | (f2bf(e1)<<16)), (int)(f2bf(e2) | (f2bf(e3)<<16)), \
        (int)(f2bf(e4) | (f2bf(e5)<<16)), (int)(f2bf(e6) | (f2bf(e7)<<16))); \
    short8 pf_ = *(short8*)&pw_; \
    acc0 = MFMA16(vf0, pf_, acc0); \
    acc1 = MFMA16(vf1, pf_, acc1); } while(0)

    // prologue: chunk 0
    LOAD_ALL(0);
    bm0 &= ~1u;                         // col 0 force-unmasked

    #pragma unroll 1
    for (int cc = 0; cc < 16; ++cc){
        // stage bias chunk cc (16 coalesced-sourced scalar writes)
        STAGE1(br0, 0); STAGE1(br1, 1); STAGE1(br2, 2); STAGE1(br3, 3);
        // snapshot K/mask of current chunk BEFORE reload (r6 lesson)
        short8 ck0 = kn0, ck1 = kn1, ck2 = kn2, ck3 = kn3;
        unsigned int cb0 = bm0, cb1 = bm1;
        if (cc + 1 < 16) LOAD_ALL(cc + 1);
        __syncthreads();

        CHUNK_HALF(ck0, ck1, cb0, 0, cc*64);
        CHUNK_HALF(ck2, ck3, cb1, 1, cc*64 + 32);
        __syncthreads();
    }

    float ps = lsum;
    ps += __shfl_xor(ps, 16);
    ps += __shfl_xor(ps, 32);
    float inv = 1.0f / ps;
    {
        int n = q0 + ln;
        unsigned int lo0 = f2bf(acc0[0]*inv) | (f2bf(acc0[1]*inv)<<16);
        unsigned int hi0 = f2bf(acc0[2]*inv) | (f2bf(acc0[3]*inv)<<16);
        *(uint2*)(ab + ((size_t)(b*1024 + n))*256 + w*32 + g*4) = make_uint2(lo0,hi0);
        unsigned int lo1 = f2bf(acc1[0]*inv) | (f2bf(acc1[1]*inv)<<16);
        unsigned int hi1 = f2bf(acc1[2]*inv) | (f2bf(acc1[3]*inv)<<16);
        *(uint2*)(ab + ((size_t)(b*1024 + n))*256 + w*32 + 16 + g*4) = make_uint2(lo1,hi1);
    }
#undef LOAD_ALL
#undef STAGE1
#undef CHUNK_HALF
}

// ---------------- Output projection (32-row tiles) ----------------
__global__ __launch_bounds__(256) void oproj_k(
    const unsigned short* __restrict__ ab, const float* __restrict__ Wop,
    const float* __restrict__ bop, float* __restrict__ out)
{
    __shared__ __align__(16) unsigned short al[32*264];
    const int tid = threadIdx.x;
    const int R0 = blockIdx.x * 32;   // 256 blocks
    #pragma unroll
    for (int it=0; it<4; ++it){
        int f8 = it*256 + tid;
        int r = f8 >> 5, c8 = f8 & 31;
        *(short8*)&al[r*264 + c8*8] = *(const short8*)(ab + (size_t)(R0+r)*256 + c8*8);
    }
    __syncthreads();
    const int lane = tid & 63;
    const int w = tid >> 6, ln = lane & 15, g = lane >> 4;
    const int ow = w*64;
    f32x4 acc[4][2];
    #pragma unroll
    for (int a=0;a<4;++a){ acc[a][0]=(f32x4){0.f,0.f,0.f,0.f}; acc[a][1]=(f32x4){0.f,0.f,0.f,0.f}; }
    for (int kk=0;kk<8;++kk){
        short8 wf[4], xf[2];
        #pragma unroll
        for (int ot=0;ot<4;++ot){
            const float* wp = Wop + (size_t)(ow+ot*16+ln)*256 + kk*32 + g*8;
            wf[ot] = pack8(*(const float4*)wp, *(const float4*)(wp+4));
        }
        #pragma unroll
        for (int nt=0;nt<2;++nt)
            xf[nt] = *(const short8*)&al[(nt*16+ln)*264 + kk*32 + g*8];
        #pragma unroll
        for (int ot=0;ot<4;++ot){
            #pragma unroll
            for (int nt=0;nt<2;++nt)
                acc[ot][nt] = MFMA16(wf[ot], xf[nt], acc[ot][nt]);
        }
    }
    #pragma unroll
    for (int ot=0;ot<4;++ot){
        int o0 = ow + ot*16 + g*4;
        float4 b4 = *(const float4*)(bop + o0);
        #pragma unroll
        for (int nt=0;nt<2;++nt){
            int n = R0 + nt*16 + ln;
            float4 res;
            res.x = acc[ot][nt][0] + b4.x;
            res.y = acc[ot][nt][1] + b4.y;
            res.z = acc[ot][nt][2] + b4.z;
            res.w = acc[ot][nt][3] + b4.w;
            *(float4*)(out + (size_t)n*256 + o0) = res;
        }
    }
}

extern "C" void kernel_launch(void* const* d_in, const int* in_sizes, int n_in,
                              void* d_out, int out_size, void* d_ws, size_t ws_size,
                              hipStream_t stream)
{
    (void)in_sizes; (void)n_in; (void)out_size; (void)ws_size;
    const float* nd   = (const float*)d_in[0];
    // d_in[1] = N scalar (compile-time 1024 here)
    const float* bias = (const float*)d_in[2];
    const int* mask   = (const int*)d_in[3];
    const float* Wq = (const float*)d_in[4];
    const float* bq = (const float*)d_in[5];
    const float* Wk = (const float*)d_in[6];
    const float* bk = (const float*)d_in[7];
    const float* Wv = (const float*)d_in[8];
    const float* bv = (const float*)d_in[9];
    const float* Wo = (const float*)d_in[10];
    const float* bo = (const float*)d_in[11];
    float* out = (float*)d_out;

    const size_t ELEMS = (size_t)8*8*1024*32;   // 2M bf16 per buffer
    unsigned short* qb  = (unsigned short*)d_ws;
    unsigned short* kb  = qb  + ELEMS;
    unsigned short* vtb = kb  + ELEMS;
    unsigned short* ab  = vtb + ELEMS;
    unsigned int* bmw   = (unsigned int*)(ab + ELEMS);  // 1MB bitmask

    qkv_mask_k<<<1408, 256, 0, stream>>>(nd, Wq, bq, Wk, bk, Wv, bv,
                                         qb, kb, vtb,
                                         (const unsigned int*)mask, bmw);
    attn_k<<<512, 512, 0, stream>>>(qb, kb, vtb, bias, bmw, ab);
    oproj_k<<<256, 256, 0, stream>>>(ab, Wo, bo, out);
}